// Round 1
// baseline (1299.872 us; speedup 1.0000x reference)
//
#include <hip/hip_runtime.h>

constexpr int NN = 100000;
constexpr int NE = 1600000;
constexpr int D  = 64;
constexpr int HD = 512;
constexpr int OD = 64;

// ---------------- CSR build ----------------
__global__ void k_count(const int* __restrict__ dst, int* __restrict__ cnt){
  int e = blockIdx.x*256 + threadIdx.x;
  if (e < NE) atomicAdd(&cnt[dst[e]], 1);
}

__global__ void k_scan_blocks(const int* __restrict__ cnt, int* __restrict__ rowptr,
                              int* __restrict__ part){
  __shared__ int s[256];
  int t = threadIdx.x;
  int i = blockIdx.x*256 + t;
  int v = (i < NN) ? cnt[i] : 0;
  s[t] = v; __syncthreads();
  #pragma unroll
  for (int off = 1; off < 256; off <<= 1){
    int tv = (t >= off) ? s[t-off] : 0;
    __syncthreads();
    s[t] += tv;
    __syncthreads();
  }
  if (i < NN) rowptr[i] = s[t] - v;          // exclusive within chunk
  if (t == 255) part[blockIdx.x] = s[255];   // chunk total
}

__global__ void k_scan_part(int* __restrict__ part, int nb){
  __shared__ int s[512];
  int t = threadIdx.x;
  int v = (t < nb) ? part[t] : 0;
  s[t] = v; __syncthreads();
  #pragma unroll
  for (int off = 1; off < 512; off <<= 1){
    int tv = (t >= off) ? s[t-off] : 0;
    __syncthreads();
    s[t] += tv;
    __syncthreads();
  }
  if (t < nb) part[t] = s[t] - v;            // exclusive
}

__global__ void k_scan_add(int* __restrict__ rowptr, const int* __restrict__ part){
  int i = blockIdx.x*256 + threadIdx.x;
  if (i < NN) rowptr[i] += part[blockIdx.x];
  if (blockIdx.x == 0 && threadIdx.x == 0) rowptr[NN] = NE;
}

__global__ void k_place(const int* __restrict__ srcA, const int* __restrict__ dstA,
                        const int* __restrict__ rowptr, int* __restrict__ cursor,
                        int* __restrict__ csr){
  int e = blockIdx.x*256 + threadIdx.x;
  if (e < NE){
    int s = srcA[e], d = dstA[e];
    int pos = atomicAdd(&cursor[d], 1);
    csr[rowptr[d] + pos] = s;
  }
}

// ---------------- hop aggregation: one wave per node, lane = feature ----------------
__global__ void k_agg(const float* __restrict__ h, const int* __restrict__ rowptr,
                      const int* __restrict__ csr, float* __restrict__ out){
  int lane = threadIdx.x & 63;
  int n = blockIdx.x*4 + (threadIdx.x >> 6);
  int beg = rowptr[n], end = rowptr[n+1];
  float s = 0.f;
  for (int e = beg; e < end; ++e){
    s += h[(size_t)csr[e]*D + lane];
  }
  float deg = (float)(end - beg);
  s /= fmaxf(deg, 1.f);
  out[(size_t)n*D + lane] = s;
}

// ---------------- in-place 64x64 GEMM: z = z @ W ----------------
__global__ void k_hopgemm(float* __restrict__ z, const float* __restrict__ W){
  __shared__ float sW[64*64];
  __shared__ float sA[16*64];
  int tid = threadIdx.x;
  const float4* W4 = (const float4*)W;
  for (int i = tid; i < 1024; i += 256) ((float4*)sW)[i] = W4[i];
  size_t base = (size_t)blockIdx.x * 16 * 64;
  const float4* z4 = (const float4*)(z + base);
  for (int i = tid; i < 256; i += 256) ((float4*)sA)[i] = z4[i];
  __syncthreads();
  int n = tid >> 4, c = tid & 15;
  float4 acc = make_float4(0.f, 0.f, 0.f, 0.f);
  #pragma unroll
  for (int d = 0; d < 64; ++d){
    float a = sA[n*64 + d];
    const float4 w = *(const float4*)&sW[d*64 + c*4];
    acc.x = fmaf(a, w.x, acc.x); acc.y = fmaf(a, w.y, acc.y);
    acc.z = fmaf(a, w.z, acc.z); acc.w = fmaf(a, w.w, acc.w);
  }
  *(float4*)&z[base + (size_t)n*64 + c*4] = acc;
}

// ---------------- fused MLP: lin1 + LN + ReLU + lin2 ----------------
__device__ inline void fma4(float4& a, float s, const float4& w){
  a.x = fmaf(s, w.x, a.x); a.y = fmaf(s, w.y, a.y);
  a.z = fmaf(s, w.z, a.z); a.w = fmaf(s, w.w, a.w);
}

__global__ __launch_bounds__(256) void k_mlp(
    const float* __restrict__ x,  const float* __restrict__ z1,
    const float* __restrict__ z2, const float* __restrict__ z3,
    const float* __restrict__ W1, const float* __restrict__ b1,
    const float* __restrict__ gamma, const float* __restrict__ beta,
    const float* __restrict__ W2, const float* __restrict__ b2,
    float* __restrict__ out){
  constexpr int WSTR = 520;                 // padded row stride (floats): 520%32=8 -> no bank conflict
  __shared__ float cbuf[16*256];            // concat tile  (16 KB)
  __shared__ float wbuf[16*WSTR];           // W1 chunk / later h-relu tile (32.5 KB)
  int tid = threadIdx.x;
  int nbase = blockIdx.x * 16;

  // stage concat rows: [x | z1 | z2 | z3]
  const float* parts[4] = {x, z1, z2, z3};
  #pragma unroll
  for (int p = 0; p < 4; ++p){
    const float4* sp = (const float4*)(parts[p] + (size_t)nbase*64);
    int i = tid;
    if (i < 256){
      int node = i >> 4, d4 = i & 15;
      *(float4*)&cbuf[node*256 + p*64 + d4*4] = sp[i];
    }
  }

  int jg = tid & 63;    // column group: j = k*256 + jg*4 + q
  int wv = tid >> 6;    // wave id -> nodes wv*4 .. wv*4+3
  float4 acc[4][2];
  #pragma unroll
  for (int i = 0; i < 4; ++i){
    acc[i][0] = make_float4(0.f,0.f,0.f,0.f);
    acc[i][1] = make_float4(0.f,0.f,0.f,0.f);
  }

  for (int dc = 0; dc < 256; dc += 16){
    __syncthreads();                         // cbuf ready / prev wbuf reads done
    for (int i = tid; i < 2048; i += 256){   // stage W1[dc..dc+15][0..511]
      int row = i >> 7, c4 = i & 127;
      *(float4*)&wbuf[row*WSTR + c4*4] = ((const float4*)(W1 + (size_t)(dc+row)*512))[c4];
    }
    __syncthreads();
    #pragma unroll
    for (int dd = 0; dd < 16; ++dd){
      float a0 = cbuf[(wv*4+0)*256 + dc+dd];
      float a1 = cbuf[(wv*4+1)*256 + dc+dd];
      float a2 = cbuf[(wv*4+2)*256 + dc+dd];
      float a3 = cbuf[(wv*4+3)*256 + dc+dd];
      const float4 w0 = *(const float4*)&wbuf[dd*WSTR + jg*4];
      const float4 w1 = *(const float4*)&wbuf[dd*WSTR + 256 + jg*4];
      fma4(acc[0][0], a0, w0); fma4(acc[0][1], a0, w1);
      fma4(acc[1][0], a1, w0); fma4(acc[1][1], a1, w1);
      fma4(acc[2][0], a2, w0); fma4(acc[2][1], a2, w1);
      fma4(acc[3][0], a3, w0); fma4(acc[3][1], a3, w1);
    }
  }
  __syncthreads();                            // wbuf reads done; reuse as h tile

  // bias
  const float4 bv0 = ((const float4*)b1)[jg];
  const float4 bv1 = ((const float4*)b1)[64 + jg];
  #pragma unroll
  for (int i = 0; i < 4; ++i){
    acc[i][0].x += bv0.x; acc[i][0].y += bv0.y; acc[i][0].z += bv0.z; acc[i][0].w += bv0.w;
    acc[i][1].x += bv1.x; acc[i][1].y += bv1.y; acc[i][1].z += bv1.z; acc[i][1].w += bv1.w;
  }

  // LN stats: reduce over the 64 lanes of this wave (each holds 8 j's per node)
  float mean[4], rstd[4];
  #pragma unroll
  for (int i = 0; i < 4; ++i){
    float s  = acc[i][0].x + acc[i][0].y + acc[i][0].z + acc[i][0].w
             + acc[i][1].x + acc[i][1].y + acc[i][1].z + acc[i][1].w;
    float s2 = acc[i][0].x*acc[i][0].x + acc[i][0].y*acc[i][0].y
             + acc[i][0].z*acc[i][0].z + acc[i][0].w*acc[i][0].w
             + acc[i][1].x*acc[i][1].x + acc[i][1].y*acc[i][1].y
             + acc[i][1].z*acc[i][1].z + acc[i][1].w*acc[i][1].w;
    #pragma unroll
    for (int off = 1; off < 64; off <<= 1){
      s  += __shfl_xor(s,  off);
      s2 += __shfl_xor(s2, off);
    }
    float mu = s * (1.f/512.f);
    float var = s2 * (1.f/512.f) - mu*mu;
    mean[i] = mu;
    rstd[i] = rsqrtf(var + 1e-5f);
  }

  // normalize + relu -> store h tile into wbuf
  const float4 g0 = ((const float4*)gamma)[jg];
  const float4 g1 = ((const float4*)gamma)[64 + jg];
  const float4 e0 = ((const float4*)beta)[jg];
  const float4 e1 = ((const float4*)beta)[64 + jg];
  #pragma unroll
  for (int i = 0; i < 4; ++i){
    float4 h0, h1;
    h0.x = fmaxf((acc[i][0].x - mean[i])*rstd[i]*g0.x + e0.x, 0.f);
    h0.y = fmaxf((acc[i][0].y - mean[i])*rstd[i]*g0.y + e0.y, 0.f);
    h0.z = fmaxf((acc[i][0].z - mean[i])*rstd[i]*g0.z + e0.z, 0.f);
    h0.w = fmaxf((acc[i][0].w - mean[i])*rstd[i]*g0.w + e0.w, 0.f);
    h1.x = fmaxf((acc[i][1].x - mean[i])*rstd[i]*g1.x + e1.x, 0.f);
    h1.y = fmaxf((acc[i][1].y - mean[i])*rstd[i]*g1.y + e1.y, 0.f);
    h1.z = fmaxf((acc[i][1].z - mean[i])*rstd[i]*g1.z + e1.z, 0.f);
    h1.w = fmaxf((acc[i][1].w - mean[i])*rstd[i]*g1.w + e1.w, 0.f);
    *(float4*)&wbuf[(wv*4+i)*WSTR + jg*4] = h0;
    *(float4*)&wbuf[(wv*4+i)*WSTR + 256 + jg*4] = h1;
  }
  __syncthreads();

  // GEMM2: out[n][o] = b2[o] + sum_j h[n][j] * W2[j][o]
  int og = tid & 15, n2 = tid >> 4;
  float4 o4 = ((const float4*)b2)[og];
  const float* hrow = &wbuf[n2*WSTR];
  for (int j4 = 0; j4 < 128; ++j4){
    const float4 hv = *(const float4*)&hrow[j4*4];
    const float4* w2r = (const float4*)(W2 + (size_t)j4*4*64);
    const float4 wa = w2r[og], wb = w2r[16+og], wc = w2r[32+og], wd = w2r[48+og];
    fma4(o4, hv.x, wa); fma4(o4, hv.y, wb); fma4(o4, hv.z, wc); fma4(o4, hv.w, wd);
  }
  *(float4*)&out[(size_t)(nbase+n2)*64 + og*4] = o4;
}

extern "C" void kernel_launch(void* const* d_in, const int* in_sizes, int n_in,
                              void* d_out, int out_size, void* d_ws, size_t ws_size,
                              hipStream_t stream){
  const float* x     = (const float*)d_in[0];
  const int*   eidx  = (const int*)d_in[1];
  const float* wprop = (const float*)d_in[2];
  const float* W1    = (const float*)d_in[3];
  const float* b1    = (const float*)d_in[4];
  const float* gamma = (const float*)d_in[5];
  const float* beta  = (const float*)d_in[6];
  const float* W2    = (const float*)d_in[7];
  const float* b2    = (const float*)d_in[8];
  float* out = (float*)d_out;
  const int* srcA = eidx;
  const int* dstA = eidx + NE;

  char* ws = (char*)d_ws;
  int*   rowptr = (int*)(ws);                 // (NN+1) ints
  int*   cursor = (int*)(ws + 400128);        // NN ints
  int*   part   = (int*)(ws + 800256);        // 1024 ints
  int*   csr    = (int*)(ws + 804352);        // NE ints
  float* z1     = (float*)(ws + 7204352);     // NN*64 floats
  float* z2     = (float*)(ws + 32804352);
  float* z3     = (float*)(ws + 58404352);    // ends at 84,004,352 bytes

  hipMemsetAsync(cursor, 0, NN*sizeof(int), stream);
  k_count<<<6250, 256, 0, stream>>>(dstA, cursor);
  k_scan_blocks<<<391, 256, 0, stream>>>(cursor, rowptr, part);
  k_scan_part<<<1, 512, 0, stream>>>(part, 391);
  k_scan_add<<<391, 256, 0, stream>>>(rowptr, part);
  hipMemsetAsync(cursor, 0, NN*sizeof(int), stream);
  k_place<<<6250, 256, 0, stream>>>(srcA, dstA, rowptr, cursor, csr);

  const float* prev = x;
  float* zb[3] = {z1, z2, z3};
  for (int hop = 0; hop < 3; ++hop){
    k_agg<<<25000, 256, 0, stream>>>(prev, rowptr, csr, zb[hop]);
    k_hopgemm<<<6250, 256, 0, stream>>>(zb[hop], wprop + hop*64*64);
    prev = zb[hop];
  }
  k_mlp<<<6250, 256, 0, stream>>>(x, z1, z2, z3, W1, b1, gamma, beta, W2, b2, out);
}

// Round 2
// 846.051 us; speedup vs baseline: 1.5364x; 1.5364x over previous
//
#include <hip/hip_runtime.h>

constexpr int NN = 100000;
constexpr int NE = 1600000;
constexpr int D  = 64;
constexpr int HD = 512;
constexpr int OD = 64;

typedef __attribute__((ext_vector_type(8))) short bf16x8;
typedef __attribute__((ext_vector_type(4))) float f32x4;

__device__ inline ushort f2b(float f){
  uint u = __float_as_uint(f);
  uint r = (u + 0x7FFFu + ((u >> 16) & 1u)) >> 16;
  return (ushort)r;
}

// ---------------- CSR build ----------------
__global__ void k_count(const int* __restrict__ dst, int* __restrict__ cnt){
  int e = blockIdx.x*256 + threadIdx.x;
  if (e < NE) atomicAdd(&cnt[dst[e]], 1);
}

__global__ void k_scan_blocks(const int* __restrict__ cnt, int* __restrict__ rowptr,
                              int* __restrict__ part){
  __shared__ int s[256];
  int t = threadIdx.x;
  int i = blockIdx.x*256 + t;
  int v = (i < NN) ? cnt[i] : 0;
  s[t] = v; __syncthreads();
  #pragma unroll
  for (int off = 1; off < 256; off <<= 1){
    int tv = (t >= off) ? s[t-off] : 0;
    __syncthreads();
    s[t] += tv;
    __syncthreads();
  }
  if (i < NN) rowptr[i] = s[t] - v;
  if (t == 255) part[blockIdx.x] = s[255];
}

__global__ void k_scan_part(int* __restrict__ part, int nb){
  __shared__ int s[512];
  int t = threadIdx.x;
  int v = (t < nb) ? part[t] : 0;
  s[t] = v; __syncthreads();
  #pragma unroll
  for (int off = 1; off < 512; off <<= 1){
    int tv = (t >= off) ? s[t-off] : 0;
    __syncthreads();
    s[t] += tv;
    __syncthreads();
  }
  if (t < nb) part[t] = s[t] - v;
}

__global__ void k_scan_add(int* __restrict__ rowptr, const int* __restrict__ part){
  int i = blockIdx.x*256 + threadIdx.x;
  if (i < NN) rowptr[i] += part[blockIdx.x];
  if (blockIdx.x == 0 && threadIdx.x == 0) rowptr[NN] = NE;
}

__global__ void k_place(const int* __restrict__ srcA, const int* __restrict__ dstA,
                        const int* __restrict__ rowptr, int* __restrict__ cursor,
                        int* __restrict__ csr){
  int e = blockIdx.x*256 + threadIdx.x;
  if (e < NE){
    int s = srcA[e], d = dstA[e];
    int pos = atomicAdd(&cursor[d], 1);
    csr[rowptr[d] + pos] = s;
  }
}

// ---------------- weight transpose+bf16 prep ----------------
__global__ void k_w1t(const float* __restrict__ W1, ushort* __restrict__ W1t){
  int col = blockIdx.x, k = threadIdx.x;           // 512 blocks x 256 threads
  W1t[col*256 + k] = f2b(W1[(size_t)k*512 + col]);
}
__global__ void k_w2t(const float* __restrict__ W2, ushort* __restrict__ W2t){
  int col = blockIdx.x, k = threadIdx.x;           // 64 blocks x 512 threads
  W2t[col*512 + k] = f2b(W2[(size_t)k*64 + col]);
}

// ---------------- hop aggregation ----------------
__global__ void k_agg(const float* __restrict__ h, const int* __restrict__ rowptr,
                      const int* __restrict__ csr, float* __restrict__ out){
  int lane = threadIdx.x & 63;
  int n = blockIdx.x*4 + (threadIdx.x >> 6);
  int beg = rowptr[n], end = rowptr[n+1];
  float s = 0.f;
  for (int e = beg; e < end; ++e){
    s += h[(size_t)csr[e]*D + lane];
  }
  float deg = (float)(end - beg);
  s /= fmaxf(deg, 1.f);
  out[(size_t)n*D + lane] = s;
}

// ---------------- in-place 64x64 GEMM: z = z @ W ----------------
__global__ void k_hopgemm(float* __restrict__ z, const float* __restrict__ W){
  __shared__ float sW[64*64];
  __shared__ float sA[16*64];
  int tid = threadIdx.x;
  const float4* W4 = (const float4*)W;
  for (int i = tid; i < 1024; i += 256) ((float4*)sW)[i] = W4[i];
  size_t base = (size_t)blockIdx.x * 16 * 64;
  const float4* z4 = (const float4*)(z + base);
  for (int i = tid; i < 256; i += 256) ((float4*)sA)[i] = z4[i];
  __syncthreads();
  int n = tid >> 4, c = tid & 15;
  float4 acc = make_float4(0.f, 0.f, 0.f, 0.f);
  #pragma unroll
  for (int d = 0; d < 64; ++d){
    float a = sA[n*64 + d];
    const float4 w = *(const float4*)&sW[d*64 + c*4];
    acc.x = fmaf(a, w.x, acc.x); acc.y = fmaf(a, w.y, acc.y);
    acc.z = fmaf(a, w.z, acc.z); acc.w = fmaf(a, w.w, acc.w);
  }
  *(float4*)&z[base + (size_t)n*64 + c*4] = acc;
}

// ---------------- fused MLP via bf16 MFMA ----------------
// block: 64 nodes, 512 threads (8 waves). Wave wv owns cols [wv*64, wv*64+64) of GEMM1.
__global__ __launch_bounds__(512) void k_mlp(
    const float* __restrict__ x,  const float* __restrict__ z1,
    const float* __restrict__ z2, const float* __restrict__ z3,
    const ushort* __restrict__ W1t, const float* __restrict__ b1,
    const float* __restrict__ gamma, const float* __restrict__ beta,
    const ushort* __restrict__ W2t, const float* __restrict__ b2,
    float* __restrict__ out){
  __shared__ char lbuf[65536];        // phase1: A tile 64x256 bf16 (32KB); phase2: h tile 64x512 bf16 (64KB)
  __shared__ float s_sum[8][64];
  __shared__ float s_sq[8][64];
  __shared__ float s_stat[64][2];

  int tid = threadIdx.x;
  int lane = tid & 63, wv = tid >> 6;
  int l15 = lane & 15, l4 = lane >> 4;
  int nbase = blockIdx.x * 64;

  // ---- stage A: concat [x|z1|z2|z3] rows nbase..nbase+63 as bf16, XOR-swizzled ----
  {
    int part = tid >> 7;              // 0..3, fixed per thread
    int w = tid & 127;
    const float* src = (part == 0) ? x : (part == 1) ? z1 : (part == 2) ? z2 : z3;
    #pragma unroll
    for (int it = 0; it < 8; ++it){
      int idx = it*128 + w;           // 0..1023 : row*16 + d4
      int row = idx >> 4, d4 = idx & 15;
      float4 v = make_float4(0.f,0.f,0.f,0.f);
      if (nbase + row < NN)
        v = ((const float4*)(src + (size_t)(nbase+row)*64))[d4];
      ushort4 bv;
      bv.x = f2b(v.x); bv.y = f2b(v.y); bv.z = f2b(v.z); bv.w = f2b(v.w);
      int byte = row*512 + ((part*128 + d4*8) ^ ((row&7)<<4));
      *(ushort4*)(lbuf + byte) = bv;
    }
  }
  __syncthreads();

  // ---- GEMM1: [64 x 256] @ [256 x 512] -> acc[rt][ci] (wave's 64-col slice) ----
  f32x4 acc[4][4] = {};
  for (int kb = 0; kb < 8; ++kb){
    bf16x8 a[4], b[4];
    #pragma unroll
    for (int rt = 0; rt < 4; ++rt){
      int row = rt*16 + l15;
      int byte = row*512 + (((kb*32 + l4*8)*2) ^ ((row&7)<<4));
      a[rt] = *(const bf16x8*)(lbuf + byte);
    }
    #pragma unroll
    for (int ci = 0; ci < 4; ++ci){
      int col = wv*64 + ci*16 + l15;
      b[ci] = *(const bf16x8*)(W1t + (size_t)col*256 + kb*32 + l4*8);
    }
    #pragma unroll
    for (int rt = 0; rt < 4; ++rt)
      #pragma unroll
      for (int ci = 0; ci < 4; ++ci)
        acc[rt][ci] = __builtin_amdgcn_mfma_f32_16x16x32_bf16(a[rt], b[ci], acc[rt][ci], 0, 0, 0);
  }

  // ---- bias + LN partial stats (per-row sum/sumsq over this wave's 64 cols) ----
  float bcol[4], gcol[4], ecol[4];
  #pragma unroll
  for (int ci = 0; ci < 4; ++ci){
    int col = wv*64 + ci*16 + l15;
    bcol[ci] = b1[col]; gcol[ci] = gamma[col]; ecol[ci] = beta[col];
  }
  #pragma unroll
  for (int rt = 0; rt < 4; ++rt)
    #pragma unroll
    for (int ci = 0; ci < 4; ++ci)
      #pragma unroll
      for (int r = 0; r < 4; ++r)
        acc[rt][ci][r] += bcol[ci];

  #pragma unroll
  for (int rt = 0; rt < 4; ++rt){
    #pragma unroll
    for (int r = 0; r < 4; ++r){
      float s = 0.f, q = 0.f;
      #pragma unroll
      for (int ci = 0; ci < 4; ++ci){
        float v = acc[rt][ci][r];
        s += v; q += v*v;
      }
      #pragma unroll
      for (int off = 1; off < 16; off <<= 1){
        s += __shfl_xor(s, off);
        q += __shfl_xor(q, off);
      }
      if (l15 == 0){
        int row = rt*16 + l4*4 + r;
        s_sum[wv][row] = s;
        s_sq[wv][row]  = q;
      }
    }
  }
  __syncthreads();            // also: all lbuf (A) reads done

  if (tid < 64){
    float s = 0.f, q = 0.f;
    #pragma unroll
    for (int w = 0; w < 8; ++w){ s += s_sum[w][tid]; q += s_sq[w][tid]; }
    float mu = s * (1.f/512.f);
    float var = q * (1.f/512.f) - mu*mu;
    s_stat[tid][0] = mu;
    s_stat[tid][1] = rsqrtf(var + 1e-5f);
  }
  __syncthreads();

  // ---- LN + ReLU -> h tile (bf16, swizzled) into lbuf ----
  #pragma unroll
  for (int rt = 0; rt < 4; ++rt){
    #pragma unroll
    for (int r = 0; r < 4; ++r){
      int row = rt*16 + l4*4 + r;
      float mu = s_stat[row][0], rs = s_stat[row][1];
      #pragma unroll
      for (int ci = 0; ci < 4; ++ci){
        float hv = fmaxf((acc[rt][ci][r] - mu)*rs*gcol[ci] + ecol[ci], 0.f);
        int col = wv*64 + ci*16 + l15;
        *(ushort*)(lbuf + row*1024 + ((col*2) ^ ((row&7)<<4))) = f2b(hv);
      }
    }
  }
  __syncthreads();

  // ---- GEMM2: h[64x512] @ W2[512x64]; wave -> ct = wv>>1, row-tile pair (wv&1)*2 ----
  int ct = wv >> 1;
  int rtb = (wv & 1) * 2;
  f32x4 acc2[2] = {};
  for (int kb = 0; kb < 16; ++kb){
    bf16x8 bfrag = *(const bf16x8*)(W2t + (size_t)(ct*16 + l15)*512 + kb*32 + l4*8);
    #pragma unroll
    for (int t = 0; t < 2; ++t){
      int row = (rtb + t)*16 + l15;
      int byte = row*1024 + (((kb*32 + l4*8)*2) ^ ((row&7)<<4));
      bf16x8 afrag = *(const bf16x8*)(lbuf + byte);
      acc2[t] = __builtin_amdgcn_mfma_f32_16x16x32_bf16(afrag, bfrag, acc2[t], 0, 0, 0);
    }
  }
  float b2v = b2[ct*16 + l15];
  #pragma unroll
  for (int t = 0; t < 2; ++t){
    #pragma unroll
    for (int r = 0; r < 4; ++r){
      int row = (rtb + t)*16 + l4*4 + r;
      if (nbase + row < NN)
        out[(size_t)(nbase + row)*64 + ct*16 + l15] = acc2[t][r] + b2v;
    }
  }
}

extern "C" void kernel_launch(void* const* d_in, const int* in_sizes, int n_in,
                              void* d_out, int out_size, void* d_ws, size_t ws_size,
                              hipStream_t stream){
  const float* x     = (const float*)d_in[0];
  const int*   eidx  = (const int*)d_in[1];
  const float* wprop = (const float*)d_in[2];
  const float* W1    = (const float*)d_in[3];
  const float* b1    = (const float*)d_in[4];
  const float* gamma = (const float*)d_in[5];
  const float* beta  = (const float*)d_in[6];
  const float* W2    = (const float*)d_in[7];
  const float* b2    = (const float*)d_in[8];
  float* out = (float*)d_out;
  const int* srcA = eidx;
  const int* dstA = eidx + NE;

  char* ws = (char*)d_ws;
  int*    rowptr = (int*)(ws);                 // (NN+1) ints
  int*    cursor = (int*)(ws + 400128);        // NN ints (dead after k_place)
  ushort* W1t    = (ushort*)(ws + 400128);     // reuses cursor region: 512*256*2 = 256KB
  ushort* W2t    = (ushort*)(ws + 662272);     // 64*512*2 = 64KB, ends 727808 < 800256
  int*    part   = (int*)(ws + 800256);        // 1024 ints
  int*    csr    = (int*)(ws + 804352);        // NE ints
  float*  z1     = (float*)(ws + 7204352);     // NN*64 floats
  float*  z2     = (float*)(ws + 32804352);
  float*  z3     = (float*)(ws + 58404352);    // ends at 84,004,352 bytes

  hipMemsetAsync(cursor, 0, NN*sizeof(int), stream);
  k_count<<<6250, 256, 0, stream>>>(dstA, cursor);
  k_scan_blocks<<<391, 256, 0, stream>>>(cursor, rowptr, part);
  k_scan_part<<<1, 512, 0, stream>>>(part, 391);
  k_scan_add<<<391, 256, 0, stream>>>(rowptr, part);
  hipMemsetAsync(cursor, 0, NN*sizeof(int), stream);
  k_place<<<6250, 256, 0, stream>>>(srcA, dstA, rowptr, cursor, csr);

  // cursor dead -> region becomes W1t/W2t
  k_w1t<<<512, 256, 0, stream>>>(W1, W1t);
  k_w2t<<<64, 512, 0, stream>>>(W2, W2t);

  const float* prev = x;
  float* zb[3] = {z1, z2, z3};
  for (int hop = 0; hop < 3; ++hop){
    k_agg<<<25000, 256, 0, stream>>>(prev, rowptr, csr, zb[hop]);
    k_hopgemm<<<6250, 256, 0, stream>>>(zb[hop], wprop + hop*64*64);
    prev = zb[hop];
  }
  k_mlp<<<1563, 512, 0, stream>>>(x, z1, z2, z3, W1t, b1, gamma, beta, W2t, b2, out);
}

// Round 3
// 498.303 us; speedup vs baseline: 2.6086x; 1.6979x over previous
//
#include <hip/hip_runtime.h>

constexpr int NN = 100000;
constexpr int NE = 1600000;

typedef __attribute__((ext_vector_type(8))) short bf16x8;
typedef __attribute__((ext_vector_type(4))) float f32x4;

__device__ inline ushort f2b(float f){
  uint u = __float_as_uint(f);
  uint r = (u + 0x7FFFu + ((u >> 16) & 1u)) >> 16;
  return (ushort)r;
}
__device__ inline ushort f2h(float f){
  _Float16 h = (_Float16)f; ushort u; __builtin_memcpy(&u, &h, 2); return u;
}
__device__ inline float h2f(ushort u){
  _Float16 h; __builtin_memcpy(&h, &u, 2); return (float)h;
}

// ---------------- CSR build ----------------
__global__ void k_count(const int* __restrict__ dst, int* __restrict__ cnt){
  int e = blockIdx.x*256 + threadIdx.x;
  if (e < NE) atomicAdd(&cnt[dst[e]], 1);
}

__global__ void k_scan_blocks(const int* __restrict__ cnt, int* __restrict__ rowptr,
                              int* __restrict__ part){
  __shared__ int s[256];
  int t = threadIdx.x;
  int i = blockIdx.x*256 + t;
  int v = (i < NN) ? cnt[i] : 0;
  s[t] = v; __syncthreads();
  #pragma unroll
  for (int off = 1; off < 256; off <<= 1){
    int tv = (t >= off) ? s[t-off] : 0;
    __syncthreads();
    s[t] += tv;
    __syncthreads();
  }
  if (i < NN) rowptr[i] = s[t] - v;
  if (t == 255) part[blockIdx.x] = s[255];
}

__global__ void k_scan_part(int* __restrict__ part, int nb){
  __shared__ int s[512];
  int t = threadIdx.x;
  int v = (t < nb) ? part[t] : 0;
  s[t] = v; __syncthreads();
  #pragma unroll
  for (int off = 1; off < 512; off <<= 1){
    int tv = (t >= off) ? s[t-off] : 0;
    __syncthreads();
    s[t] += tv;
    __syncthreads();
  }
  if (t < nb) part[t] = s[t] - v;
}

__global__ void k_scan_add(int* __restrict__ rowptr, const int* __restrict__ part){
  int i = blockIdx.x*256 + threadIdx.x;
  if (i < NN) rowptr[i] += part[blockIdx.x];
  if (blockIdx.x == 0 && threadIdx.x == 0) rowptr[NN] = NE;
}

__global__ void k_place(const int* __restrict__ srcA, const int* __restrict__ dstA,
                        const int* __restrict__ rowptr, int* __restrict__ cursor,
                        int* __restrict__ csr){
  int e = blockIdx.x*256 + threadIdx.x;
  if (e < NE){
    int s = srcA[e], d = dstA[e];
    int pos = atomicAdd(&cursor[d], 1);
    csr[rowptr[d] + pos] = s;
  }
}

// ---------------- x -> fp16 copy ----------------
__global__ void k_x16(const float* __restrict__ x, ushort* __restrict__ x16){
  int i = blockIdx.x*256 + threadIdx.x;           // per float4
  float4 v = ((const float4*)x)[i];
  ushort4 o;
  o.x = f2h(v.x); o.y = f2h(v.y); o.z = f2h(v.z); o.w = f2h(v.w);
  ((ushort4*)x16)[i] = o;
}

// ---------------- effective-weight prep ----------------
// V2 = Wp0 @ Wp1, V3 = V2 @ Wp2  (fp32, single block)
__global__ void k_vchain(const float* __restrict__ Wp, float* __restrict__ V2,
                         float* __restrict__ V3){
  __shared__ float sA[4096], sB[4096], sC[4096];
  int t = threadIdx.x;
  for (int i = t; i < 4096; i += 256){ sA[i] = Wp[i]; sB[i] = Wp[4096+i]; }
  __syncthreads();
  for (int i = t; i < 4096; i += 256){
    int r = i >> 6, c = i & 63; float s = 0.f;
    #pragma unroll 8
    for (int j = 0; j < 64; ++j) s += sA[r*64+j]*sB[j*64+c];
    sC[i] = s; V2[i] = s;
  }
  __syncthreads();
  for (int i = t; i < 4096; i += 256) sB[i] = Wp[8192+i];
  __syncthreads();
  for (int i = t; i < 4096; i += 256){
    int r = i >> 6, c = i & 63; float s = 0.f;
    #pragma unroll 8
    for (int j = 0; j < 64; ++j) s += sC[r*64+j]*sB[j*64+c];
    V3[i] = s;
  }
}

// U[k][c] for k-part p: U = [W1b[0:64]; Wp0@W1b[64:128]; V2@W1b[128:192]; V3@W1b[192:256]]
// stored transposed bf16: W1t[c*256 + k]
__global__ void k_ueff(const float* __restrict__ W1, const float* __restrict__ Wp,
                       const float* __restrict__ V2, const float* __restrict__ V3,
                       ushort* __restrict__ W1t){
  __shared__ float col[256];
  int c = blockIdx.x, r = threadIdx.x;
  col[r] = W1[(size_t)r*512 + c];
  __syncthreads();
  int p = r >> 6, i = r & 63;
  float s;
  if (p == 0) s = col[r];
  else {
    const float* V = (p == 1) ? Wp : (p == 2) ? V2 : V3;
    s = 0.f;
    #pragma unroll 8
    for (int j = 0; j < 64; ++j) s += V[i*64+j]*col[p*64+j];
  }
  W1t[c*256 + r] = f2b(s);
}

__global__ void k_w2t(const float* __restrict__ W2, ushort* __restrict__ W2t){
  int col = blockIdx.x, k = threadIdx.x;           // 64 blocks x 512 threads
  W2t[col*512 + k] = f2b(W2[(size_t)k*64 + col]);
}

// ---------------- fp16 hop aggregation: wave per node, 4 edge slots x 16 lanes ----------------
__global__ void k_agg16(const ushort* __restrict__ h16, const int* __restrict__ rowptr,
                        const int* __restrict__ csr, ushort* __restrict__ y16){
  int lane = threadIdx.x & 63;
  int n = blockIdx.x*4 + (threadIdx.x >> 6);
  int f = lane & 15, s = lane >> 4;
  int beg = rowptr[n], end = rowptr[n+1];
  float ax = 0.f, ay = 0.f, az = 0.f, aw = 0.f;
  int e = beg + s;
  for (; e + 4 < end; e += 8){
    int n0 = csr[e], n1 = csr[e+4];
    ushort4 v0 = *(const ushort4*)(h16 + (size_t)n0*64 + f*4);
    ushort4 v1 = *(const ushort4*)(h16 + (size_t)n1*64 + f*4);
    ax += h2f(v0.x) + h2f(v1.x);
    ay += h2f(v0.y) + h2f(v1.y);
    az += h2f(v0.z) + h2f(v1.z);
    aw += h2f(v0.w) + h2f(v1.w);
  }
  if (e < end){
    int n0 = csr[e];
    ushort4 v0 = *(const ushort4*)(h16 + (size_t)n0*64 + f*4);
    ax += h2f(v0.x); ay += h2f(v0.y); az += h2f(v0.z); aw += h2f(v0.w);
  }
  #pragma unroll
  for (int off = 16; off < 64; off <<= 1){
    ax += __shfl_xor(ax, off);
    ay += __shfl_xor(ay, off);
    az += __shfl_xor(az, off);
    aw += __shfl_xor(aw, off);
  }
  if (s == 0){
    float inv = 1.f / fmaxf((float)(end - beg), 1.f);
    ushort4 o;
    o.x = f2h(ax*inv); o.y = f2h(ay*inv); o.z = f2h(az*inv); o.w = f2h(aw*inv);
    *(ushort4*)(y16 + (size_t)n*64 + f*4) = o;
  }
}

// ---------------- fused MLP via bf16 MFMA, 37KB LDS -> 4 blocks/CU ----------------
__global__ __launch_bounds__(512) void k_mlp(
    const float* __restrict__ x,  const ushort* __restrict__ y1,
    const ushort* __restrict__ y2, const ushort* __restrict__ y3,
    const ushort* __restrict__ W1t, const float* __restrict__ b1,
    const float* __restrict__ gamma, const float* __restrict__ beta,
    const ushort* __restrict__ W2t, const float* __restrict__ b2,
    float* __restrict__ out){
  __shared__ char lbuf[32768];        // A tile 64x256 bf16; later h tile halves 64x256 bf16
  __shared__ float s_sum[8][64];
  __shared__ float s_sq[8][64];
  __shared__ float s_stat[64][2];

  int tid = threadIdx.x;
  int lane = tid & 63, wv = tid >> 6;
  int l15 = lane & 15, l4 = lane >> 4;
  int nbase = blockIdx.x * 64;

  // ---- stage A: concat [x|y1|y2|y3] rows as bf16, XOR-swizzled ----
  {
    int p = tid >> 7;              // 0..3
    int w = tid & 127;
    #pragma unroll
    for (int it = 0; it < 8; ++it){
      int idx = it*128 + w;        // row*16 + d4
      int row = idx >> 4, d4 = idx & 15;
      ushort4 bv;
      if (p == 0){
        float4 v = make_float4(0.f,0.f,0.f,0.f);
        if (nbase + row < NN) v = ((const float4*)(x + (size_t)(nbase+row)*64))[d4];
        bv.x = f2b(v.x); bv.y = f2b(v.y); bv.z = f2b(v.z); bv.w = f2b(v.w);
      } else {
        const ushort* src = (p == 1) ? y1 : (p == 2) ? y2 : y3;
        ushort4 v = make_ushort4(0,0,0,0);
        if (nbase + row < NN) v = ((const ushort4*)(src + (size_t)(nbase+row)*64))[d4];
        bv.x = f2b(h2f(v.x)); bv.y = f2b(h2f(v.y));
        bv.z = f2b(h2f(v.z)); bv.w = f2b(h2f(v.w));
      }
      int byte = row*512 + ((p*128 + d4*8) ^ ((row&7)<<4));
      *(ushort4*)(lbuf + byte) = bv;
    }
  }
  __syncthreads();                                          // (1)

  // ---- GEMM1: [64x256] @ [256x512], wave owns 64 cols; B register-prefetched ----
  f32x4 acc[4][4] = {};
  const ushort* wbase = W1t + (size_t)(wv*64 + l15)*256 + l4*8;
  bf16x8 bcur[4];
  #pragma unroll
  for (int ci = 0; ci < 4; ++ci) bcur[ci] = *(const bf16x8*)(wbase + ci*16*256);
  #pragma unroll
  for (int kb = 0; kb < 8; ++kb){
    bf16x8 a[4];
    #pragma unroll
    for (int rt = 0; rt < 4; ++rt){
      int row = rt*16 + l15;
      a[rt] = *(const bf16x8*)(lbuf + row*512 + (((kb*32 + l4*8)*2) ^ ((row&7)<<4)));
    }
    bf16x8 bn[4];
    if (kb < 7){
      #pragma unroll
      for (int ci = 0; ci < 4; ++ci)
        bn[ci] = *(const bf16x8*)(wbase + ci*16*256 + (kb+1)*32);
    }
    #pragma unroll
    for (int rt = 0; rt < 4; ++rt)
      #pragma unroll
      for (int ci = 0; ci < 4; ++ci)
        acc[rt][ci] = __builtin_amdgcn_mfma_f32_16x16x32_bf16(a[rt], bcur[ci], acc[rt][ci], 0, 0, 0);
    if (kb < 7){
      #pragma unroll
      for (int ci = 0; ci < 4; ++ci) bcur[ci] = bn[ci];
    }
  }

  // ---- bias + LN partial stats ----
  float bcol[4], gcol[4], ecol[4];
  #pragma unroll
  for (int ci = 0; ci < 4; ++ci){
    int col = wv*64 + ci*16 + l15;
    bcol[ci] = b1[col]; gcol[ci] = gamma[col]; ecol[ci] = beta[col];
  }
  #pragma unroll
  for (int rt = 0; rt < 4; ++rt)
    #pragma unroll
    for (int ci = 0; ci < 4; ++ci)
      #pragma unroll
      for (int r = 0; r < 4; ++r)
        acc[rt][ci][r] += bcol[ci];

  #pragma unroll
  for (int rt = 0; rt < 4; ++rt){
    #pragma unroll
    for (int r = 0; r < 4; ++r){
      float s = 0.f, q = 0.f;
      #pragma unroll
      for (int ci = 0; ci < 4; ++ci){
        float v = acc[rt][ci][r];
        s += v; q += v*v;
      }
      #pragma unroll
      for (int off = 1; off < 16; off <<= 1){
        s += __shfl_xor(s, off);
        q += __shfl_xor(q, off);
      }
      if (l15 == 0){
        int row = rt*16 + l4*4 + r;
        s_sum[wv][row] = s;
        s_sq[wv][row]  = q;
      }
    }
  }
  __syncthreads();                                          // (2) also: A reads done

  if (tid < 64){
    float s = 0.f, q = 0.f;
    #pragma unroll
    for (int w = 0; w < 8; ++w){ s += s_sum[w][tid]; q += s_sq[w][tid]; }
    float mu = s * (1.f/512.f);
    float var = q * (1.f/512.f) - mu*mu;
    s_stat[tid][0] = mu;
    s_stat[tid][1] = rsqrtf(var + 1e-5f);
  }
  __syncthreads();                                          // (3)

  // ---- LN + ReLU -> h half 1 (cols 0..255, waves 0-3) ----
  if (wv < 4){
    #pragma unroll
    for (int rt = 0; rt < 4; ++rt){
      #pragma unroll
      for (int r = 0; r < 4; ++r){
        int row = rt*16 + l4*4 + r;
        float mu = s_stat[row][0], rs = s_stat[row][1];
        #pragma unroll
        for (int ci = 0; ci < 4; ++ci){
          float hv = fmaxf((acc[rt][ci][r] - mu)*rs*gcol[ci] + ecol[ci], 0.f);
          int cl = wv*64 + ci*16 + l15;                     // local col 0..255
          *(ushort*)(lbuf + row*512 + ((cl*2) ^ ((row&7)<<4))) = f2b(hv);
        }
      }
    }
  }
  __syncthreads();                                          // (4)

  // ---- GEMM2 half 1 (k = 0..255) ----
  int ct = wv >> 1;
  int rtb = (wv & 1) * 2;
  f32x4 acc2[2] = {};
  const ushort* w2base = W2t + (size_t)(ct*16 + l15)*512 + l4*8;
  #pragma unroll
  for (int kb = 0; kb < 8; ++kb){
    bf16x8 bfrag = *(const bf16x8*)(w2base + kb*32);
    #pragma unroll
    for (int t = 0; t < 2; ++t){
      int row = (rtb + t)*16 + l15;
      bf16x8 af = *(const bf16x8*)(lbuf + row*512 + (((kb*32 + l4*8)*2) ^ ((row&7)<<4)));
      acc2[t] = __builtin_amdgcn_mfma_f32_16x16x32_bf16(af, bfrag, acc2[t], 0, 0, 0);
    }
  }
  __syncthreads();                                          // (5)

  // ---- h half 2 (cols 256..511, waves 4-7) ----
  if (wv >= 4){
    #pragma unroll
    for (int rt = 0; rt < 4; ++rt){
      #pragma unroll
      for (int r = 0; r < 4; ++r){
        int row = rt*16 + l4*4 + r;
        float mu = s_stat[row][0], rs = s_stat[row][1];
        #pragma unroll
        for (int ci = 0; ci < 4; ++ci){
          float hv = fmaxf((acc[rt][ci][r] - mu)*rs*gcol[ci] + ecol[ci], 0.f);
          int cl = (wv-4)*64 + ci*16 + l15;                 // local col 0..255
          *(ushort*)(lbuf + row*512 + ((cl*2) ^ ((row&7)<<4))) = f2b(hv);
        }
      }
    }
  }
  __syncthreads();                                          // (6)

  // ---- GEMM2 half 2 (k = 256..511) ----
  #pragma unroll
  for (int kb = 0; kb < 8; ++kb){
    bf16x8 bfrag = *(const bf16x8*)(w2base + (8+kb)*32);
    #pragma unroll
    for (int t = 0; t < 2; ++t){
      int row = (rtb + t)*16 + l15;
      bf16x8 af = *(const bf16x8*)(lbuf + row*512 + (((kb*32 + l4*8)*2) ^ ((row&7)<<4)));
      acc2[t] = __builtin_amdgcn_mfma_f32_16x16x32_bf16(af, bfrag, acc2[t], 0, 0, 0);
    }
  }

  float b2v = b2[ct*16 + l15];
  #pragma unroll
  for (int t = 0; t < 2; ++t){
    #pragma unroll
    for (int r = 0; r < 4; ++r){
      int row = (rtb + t)*16 + l4*4 + r;
      if (nbase + row < NN)
        out[(size_t)(nbase + row)*64 + ct*16 + l15] = acc2[t][r] + b2v;
    }
  }
}

extern "C" void kernel_launch(void* const* d_in, const int* in_sizes, int n_in,
                              void* d_out, int out_size, void* d_ws, size_t ws_size,
                              hipStream_t stream){
  const float* x     = (const float*)d_in[0];
  const int*   eidx  = (const int*)d_in[1];
  const float* wprop = (const float*)d_in[2];
  const float* W1    = (const float*)d_in[3];
  const float* b1    = (const float*)d_in[4];
  const float* gamma = (const float*)d_in[5];
  const float* beta  = (const float*)d_in[6];
  const float* W2    = (const float*)d_in[7];
  const float* b2    = (const float*)d_in[8];
  float* out = (float*)d_out;
  const int* srcA = eidx;
  const int* dstA = eidx + NE;

  char* ws = (char*)d_ws;
  int*    rowptr = (int*)(ws);                 // 400,128 B
  int*    cursor = (int*)(ws + 400128);        // NN ints (dead after k_place)
  ushort* W1t    = (ushort*)(ws + 400128);     // 256 KB (reuses cursor region)
  ushort* W2t    = (ushort*)(ws + 662272);     // 64 KB  -> 727,808
  float*  V2     = (float*)(ws + 727808);      // 16 KB  -> 744,192
  float*  V3     = (float*)(ws + 744192);      // 16 KB  -> 760,576
  int*    part   = (int*)(ws + 800256);        // 4 KB
  int*    csr    = (int*)(ws + 804352);        // 6.4 MB -> 7,204,352
  ushort* x16    = (ushort*)(ws + 7204352);    // 12.8 MB -> 20,004,352
  ushort* y1     = (ushort*)(ws + 20004352);   // 12.8 MB -> 32,804,352
  ushort* y2     = (ushort*)(ws + 32804352);   // 12.8 MB -> 45,604,352
  ushort* y3     = (ushort*)(ws + 45604352);   // 12.8 MB -> 58,404,352

  hipMemsetAsync(cursor, 0, NN*sizeof(int), stream);
  k_count<<<6250, 256, 0, stream>>>(dstA, cursor);
  k_scan_blocks<<<391, 256, 0, stream>>>(cursor, rowptr, part);
  k_scan_part<<<1, 512, 0, stream>>>(part, 391);
  k_scan_add<<<391, 256, 0, stream>>>(rowptr, part);
  hipMemsetAsync(cursor, 0, NN*sizeof(int), stream);
  k_place<<<6250, 256, 0, stream>>>(srcA, dstA, rowptr, cursor, csr);

  // cursor dead -> region becomes W1t/W2t/V2/V3
  k_x16<<<6250, 256, 0, stream>>>(x, x16);
  k_vchain<<<1, 256, 0, stream>>>(wprop, V2, V3);
  k_ueff<<<512, 256, 0, stream>>>(W1, wprop, V2, V3, W1t);
  k_w2t<<<64, 512, 0, stream>>>(W2, W2t);

  k_agg16<<<25000, 256, 0, stream>>>(x16, rowptr, csr, y1);
  k_agg16<<<25000, 256, 0, stream>>>(y1, rowptr, csr, y2);
  k_agg16<<<25000, 256, 0, stream>>>(y2, rowptr, csr, y3);

  k_mlp<<<1563, 512, 0, stream>>>(x, y1, y2, y3, W1t, b1, gamma, beta, W2t, b2, out);
}